// Round 11
// baseline (451.561 us; speedup 1.0000x reference)
//
#include <hip/hip_runtime.h>
#include <hip/hip_cooperative_groups.h>
#include <hip/hip_bf16.h>
#include <math.h>

#define B 4
#define T 128
#define S 512
#define H 512
// 2*log2(e): folds tanh's 2x and e->2 base change into the projection epilogue
#define QK_SCALE 2.8853900817779268f

// Hardware exp2 (v_exp_f32). Fallback = native exp path, never OCML-precise.
#if defined(__has_builtin)
#if __has_builtin(__builtin_amdgcn_exp2f)
#define EXP2F(x) __builtin_amdgcn_exp2f(x)
#else
#define EXP2F(x) __expf((x) * 0.6931471805599453f)
#endif
#else
#define EXP2F(x) __expf((x) * 0.6931471805599453f)
#endif

typedef __attribute__((ext_vector_type(8))) short bf16x8;
typedef __attribute__((ext_vector_type(4))) float f32x4;

__device__ __forceinline__ short f2b(float x) {   // f32 -> bf16 RNE
    unsigned int u = __float_as_uint(x);
    u += 0x7fffu + ((u >> 16) & 1u);
    return (short)(u >> 16);
}
__device__ __forceinline__ float fast_tanh(float x) {
    float e = __expf(2.0f * x);
    float r = __builtin_amdgcn_rcpf(e + 1.0f);
    return 1.0f - 2.0f * r;
}

#define MFMA4(APTR0, APTR1, BPTR0, BPTR1, KOFF)                                  \
    {                                                                            \
        bf16x8 a0 = *(const bf16x8*)((APTR0) + (KOFF));                          \
        bf16x8 a1 = *(const bf16x8*)((APTR1) + (KOFF));                          \
        bf16x8 b0 = *(const bf16x8*)((BPTR0) + (KOFF));                          \
        bf16x8 b1 = *(const bf16x8*)((BPTR1) + (KOFF));                          \
        acc00 = __builtin_amdgcn_mfma_f32_16x16x32_bf16(a0, b0, acc00, 0, 0, 0); \
        acc01 = __builtin_amdgcn_mfma_f32_16x16x32_bf16(a0, b1, acc01, 0, 0, 0); \
        acc10 = __builtin_amdgcn_mfma_f32_16x16x32_bf16(a1, b0, acc10, 0, 0, 0); \
        acc11 = __builtin_amdgcn_mfma_f32_16x16x32_bf16(a1, b1, acc11, 0, 0, 0); \
    }

// One cooperative kernel, 7 phases = R9's 7 kernels, grid.sync() between.
// 512 blocks x 256 threads (4 waves) = 2048 waves; every phase keeps R9's
// per-wave job shape via grid-stride loops (R10 lesson: fusion must not
// collapse wave count).
__global__ __launch_bounds__(256) void mega_kernel(
    const float* __restrict__ query, const float* __restrict__ enc,
    const int* __restrict__ slen, const float* __restrict__ Ws,
    const float* __restrict__ Wh, const float* __restrict__ v,
    const float* __restrict__ Wo, const float* __restrict__ bias,
    const float* __restrict__ gamma, const float* __restrict__ beta,
    float* __restrict__ out,
    short* __restrict__ qb, short* __restrict__ wsb, short* __restrict__ whb,
    short* __restrict__ wob, short* __restrict__ eb, short* __restrict__ encT,
    float* __restrict__ qe, float* __restrict__ ke, float* __restrict__ scoreh,
    short* __restrict__ attnb, short* __restrict__ ctxb, float* __restrict__ pre) {
    cooperative_groups::grid_group grid = cooperative_groups::this_grid();
    const int tid = threadIdx.x;
    const int wv = tid >> 6, lane = tid & 63;
    const int nblk = gridDim.x;
    const int gw = blockIdx.x * 4 + wv;      // global wave id
    const int NW = nblk * 4;                 // total waves
    const int r = lane & 15, kq = lane >> 4; // MFMA lane decomposition

    __shared__ short tb[32][33];

    // ===== Phase A: cvt to bf16 (jobs 0..1151) + encT transpose (1152..2175) =====
    for (int job = blockIdx.x; job < 2176; job += nblk) {
        if (job >= 1152) {
            const int j2 = job - 1152;
            const int b = j2 >> 8, s0 = ((j2 >> 4) & 15) * 32, h0 = (j2 & 15) * 32;
            if (s0 < slen[b]) {   // uniform per block
                const int rr = tid >> 3, c = (tid & 7) * 4;
                float4 a = *(const float4*)&enc[((size_t)(b * S + s0 + rr)) * H + h0 + c];
                tb[c + 0][rr] = f2b(a.x); tb[c + 1][rr] = f2b(a.y);
                tb[c + 2][rr] = f2b(a.z); tb[c + 3][rr] = f2b(a.w);
                __syncthreads();
                ushort4 o = make_ushort4((unsigned short)tb[rr][c], (unsigned short)tb[rr][c + 1],
                                         (unsigned short)tb[rr][c + 2], (unsigned short)tb[rr][c + 3]);
                *(ushort4*)&encT[((size_t)(b * H + h0 + rr)) * S + s0 + c] = o;
                __syncthreads();   // tb reused next iteration
            }
        } else {
            size_t i = ((size_t)job * 256 + tid) * 8;
            const float* src; short* dst; size_t off;
            if (i < 262144)        { src = query; dst = qb;  off = i; }
            else if (i < 524288)   { src = Ws;    dst = wsb; off = i - 262144; }
            else if (i < 786432)   { src = Wh;    dst = whb; off = i - 524288; }
            else if (i < 1310720)  { src = Wo;    dst = wob; off = i - 786432; }
            else                   { src = enc;   dst = eb;  off = i - 1310720; }
            float4 a = *(const float4*)(src + off);
            float4 b4 = *(const float4*)(src + off + 4);
            ushort4 o0 = make_ushort4((unsigned short)f2b(a.x), (unsigned short)f2b(a.y),
                                      (unsigned short)f2b(a.z), (unsigned short)f2b(a.w));
            ushort4 o1 = make_ushort4((unsigned short)f2b(b4.x), (unsigned short)f2b(b4.y),
                                      (unsigned short)f2b(b4.z), (unsigned short)f2b(b4.w));
            *(ushort4*)(dst + off) = o0;
            *(ushort4*)(dst + off + 4) = o1;
        }
    }
    grid.sync();

    // ===== Phase B: projections, Eq/Ek = exp2(GEMM*2log2e); 1280 wave-jobs =====
    for (int job = gw; job < 1280; job += NW) {
        const int n0 = (job & 15) * 32;
        const int m0 = (job >> 4) * 32;
        const short* A; const short* W; float* C;
        if (m0 < 512) { A = qb + (size_t)m0 * H; W = wsb; C = qe + (size_t)m0 * H; }
        else {
            const int row = m0 - 512;
            if ((row & 511) >= slen[row >> 9]) continue;   // fully-masked k-tile
            A = eb + (size_t)row * H; W = whb; C = ke + (size_t)row * H;
        }
        const short* a0p = A + (size_t)r * H + kq * 8;
        const short* a1p = a0p + 16 * H;
        const short* b0p = W + (size_t)(n0 + r) * H + kq * 8;
        const short* b1p = b0p + 16 * H;
        f32x4 acc00 = {0,0,0,0}, acc01 = {0,0,0,0}, acc10 = {0,0,0,0}, acc11 = {0,0,0,0};
#pragma unroll 4
        for (int k = 0; k < H; k += 32) MFMA4(a0p, a1p, b0p, b1p, k)
        const int cr = kq * 4;
#pragma unroll
        for (int g = 0; g < 4; ++g) {
            C[(size_t)(cr + g) * H + n0 + r]           = EXP2F(acc00[g] * QK_SCALE);
            C[(size_t)(cr + g) * H + n0 + 16 + r]      = EXP2F(acc01[g] * QK_SCALE);
            C[(size_t)(16 + cr + g) * H + n0 + r]      = EXP2F(acc10[g] * QK_SCALE);
            C[(size_t)(16 + cr + g) * H + n0 + 16 + r] = EXP2F(acc11[g] * QK_SCALE);
        }
    }
    grid.sync();

    // ===== Phase C: score quarters; 8192 wave-jobs (masked skipped) =====
    // scoreh[qt][row][s] = -2 sum_h v[h] * rcp(Eq*Ek + 1); direct L2 reads
    for (int job = gw; job < 8192; job += NW) {
        const int sbase = (job & 31) * 16;
        const int tbase = ((job >> 5) & 15) * 8;
        const int z = job >> 9;
        const int qt = z & 3, b = z >> 2;
        if (sbase >= slen[b]) continue;
        const int hbase = qt * 128;
        const int t = lane >> 3, s2 = (lane & 7) * 2;
        const float* qrow = qe + (size_t)(b * T + tbase + t) * H + hbase;
        const float* k0r = ke + (size_t)(b * S + sbase + s2) * H + hbase;
        const float* k1r = k0r + H;
        const float* vp = v + hbase;
        float a0 = 0.f, a1 = 0.f, c0 = 0.f, c1 = 0.f;
#pragma unroll 4
        for (int i = 0; i < 128; i += 4) {
            float4 q4 = *(const float4*)(qrow + i);
            float4 ka = *(const float4*)(k0r + i);
            float4 kb2 = *(const float4*)(k1r + i);
            float4 v4 = *(const float4*)(vp + i);
            a0 = fmaf(v4.x, __builtin_amdgcn_rcpf(fmaf(q4.x, ka.x, 1.f)), a0);
            c0 = fmaf(v4.x, __builtin_amdgcn_rcpf(fmaf(q4.x, kb2.x, 1.f)), c0);
            a1 = fmaf(v4.y, __builtin_amdgcn_rcpf(fmaf(q4.y, ka.y, 1.f)), a1);
            c1 = fmaf(v4.y, __builtin_amdgcn_rcpf(fmaf(q4.y, kb2.y, 1.f)), c1);
            a0 = fmaf(v4.z, __builtin_amdgcn_rcpf(fmaf(q4.z, ka.z, 1.f)), a0);
            c0 = fmaf(v4.z, __builtin_amdgcn_rcpf(fmaf(q4.z, kb2.z, 1.f)), c0);
            a1 = fmaf(v4.w, __builtin_amdgcn_rcpf(fmaf(q4.w, ka.w, 1.f)), a1);
            c1 = fmaf(v4.w, __builtin_amdgcn_rcpf(fmaf(q4.w, kb2.w, 1.f)), c1);
        }
        *(float2*)&scoreh[((size_t)qt * (B * T) + b * T + tbase + t) * S + sbase + s2] =
            make_float2(-2.f * (a0 + a1), -2.f * (c0 + c1));
    }
    grid.sync();

    // ===== Phase D: masked softmax over 4 slices -> bf16 attn; 512 row-jobs =====
    for (int row = gw; row < B * T; row += NW) {
        const int L = slen[row >> 7];
        const size_t sl = (size_t)(B * T) * S;
        const float* p = scoreh + (size_t)row * S + lane * 8;
        float x[8];
#pragma unroll
        for (int j = 0; j < 2; ++j) {
            float4 q0 = *(const float4*)(p + j * 4);
            float4 q1 = *(const float4*)(p + sl + j * 4);
            float4 q2 = *(const float4*)(p + 2 * sl + j * 4);
            float4 q3 = *(const float4*)(p + 3 * sl + j * 4);
            x[j * 4 + 0] = q0.x + q1.x + q2.x + q3.x;
            x[j * 4 + 1] = q0.y + q1.y + q2.y + q3.y;
            x[j * 4 + 2] = q0.z + q1.z + q2.z + q3.z;
            x[j * 4 + 3] = q0.w + q1.w + q2.w + q3.w;
        }
        const int cbase = lane * 8;
#pragma unroll
        for (int j = 0; j < 8; ++j)
            if (cbase + j >= L) x[j] = -INFINITY;
        float m = x[0];
#pragma unroll
        for (int j = 1; j < 8; ++j) m = fmaxf(m, x[j]);
#pragma unroll
        for (int off = 1; off < 64; off <<= 1) m = fmaxf(m, __shfl_xor(m, off));
        float e[8], sm = 0.f;
#pragma unroll
        for (int j = 0; j < 8; ++j) { e[j] = __expf(x[j] - m); sm += e[j]; }
#pragma unroll
        for (int off = 1; off < 64; off <<= 1) sm += __shfl_xor(sm, off);
        float inv = 1.0f / sm;   // masked -> exact 0
        short* o = attnb + (size_t)row * S + lane * 8;
        ushort4 u0 = make_ushort4((unsigned short)f2b(e[0] * inv), (unsigned short)f2b(e[1] * inv),
                                  (unsigned short)f2b(e[2] * inv), (unsigned short)f2b(e[3] * inv));
        ushort4 u1 = make_ushort4((unsigned short)f2b(e[4] * inv), (unsigned short)f2b(e[5] * inv),
                                  (unsigned short)f2b(e[6] * inv), (unsigned short)f2b(e[7] * inv));
        *(ushort4*)o = u0;
        *(ushort4*)(o + 4) = u1;
    }
    grid.sync();

    // ===== Phase E: ctx = attn @ enc; 256 wave-jobs, K capped at ceil32(L) =====
    for (int job = gw; job < 256; job += NW) {
        const int n0 = (job & 15) * 32;
        const int m0 = ((job >> 4) & 3) * 32;
        const int b = job >> 6;
        const int L = slen[b];
        const int Keff = min(S, (L + 31) & ~31);
        const short* A = attnb + (size_t)(b * T + m0) * S;
        const short* Bp = encT + (size_t)b * H * S;
        const short* a0p = A + (size_t)r * S + kq * 8;
        const short* a1p = a0p + 16 * S;
        const short* b0p = Bp + (size_t)(n0 + r) * S + kq * 8;
        const short* b1p = b0p + 16 * S;
        f32x4 acc00 = {0,0,0,0}, acc01 = {0,0,0,0}, acc10 = {0,0,0,0}, acc11 = {0,0,0,0};
#pragma unroll 2
        for (int k = 0; k < Keff; k += 32) MFMA4(a0p, a1p, b0p, b1p, k)
        const int cr = kq * 4;
#pragma unroll
        for (int g = 0; g < 4; ++g) {
            size_t row0 = (size_t)(b * T + m0 + cr + g) * H;
            size_t row1 = (size_t)(b * T + m0 + 16 + cr + g) * H;
            ctxb[row0 + n0 + r]      = f2b(acc00[g]);
            ctxb[row0 + n0 + 16 + r] = f2b(acc01[g]);
            ctxb[row1 + n0 + r]      = f2b(acc10[g]);
            ctxb[row1 + n0 + 16 + r] = f2b(acc11[g]);
        }
    }
    grid.sync();

    // ===== Phase F: pre = tanh([ctx|query] @ Wo^T + bias); 256 wave-jobs =====
    for (int job = gw; job < 256; job += NW) {
        const int n0 = (job & 15) * 32;
        const int m0 = (job >> 4) * 32;   // global row (b*T+t)
        f32x4 acc00 = {0,0,0,0}, acc01 = {0,0,0,0}, acc10 = {0,0,0,0}, acc11 = {0,0,0,0};
        const short* b0p = wob + (size_t)(n0 + r) * (2 * H) + kq * 8;
        const short* b1p = b0p + 16 * (2 * H);
        {
            const short* a0p = ctxb + (size_t)(m0 + r) * H + kq * 8;
            const short* a1p = a0p + 16 * H;
#pragma unroll 4
            for (int k = 0; k < H; k += 32) MFMA4(a0p, a1p, b0p, b1p, k)
        }
        {
            const short* a0p = qb + (size_t)(m0 + r) * H + kq * 8;
            const short* a1p = a0p + 16 * H;
            const short* c0p = b0p + H;
            const short* c1p = b1p + H;
#pragma unroll 4
            for (int k = 0; k < H; k += 32) MFMA4(a0p, a1p, c0p, c1p, k)
        }
        const int cr = kq * 4;
        float bn0 = bias[n0 + r], bn1 = bias[n0 + 16 + r];
#pragma unroll
        for (int g = 0; g < 4; ++g) {
            size_t row0 = (size_t)(m0 + cr + g) * H;
            size_t row1 = (size_t)(m0 + 16 + cr + g) * H;
            pre[row0 + n0 + r]      = fast_tanh(acc00[g] + bn0);
            pre[row0 + n0 + 16 + r] = fast_tanh(acc01[g] + bn1);
            pre[row1 + n0 + r]      = fast_tanh(acc10[g] + bn0);
            pre[row1 + n0 + 16 + r] = fast_tanh(acc11[g] + bn1);
        }
    }
    grid.sync();

    // ===== Phase G: LayerNorm; 512 row-jobs, wave per row, 8 f32/lane =====
    for (int row = gw; row < B * T; row += NW) {
        const float* x = pre + (size_t)row * H + lane * 8;
        float4 xa = *(const float4*)x;
        float4 xb = *(const float4*)(x + 4);
        float s = (xa.x + xa.y) + (xa.z + xa.w) + (xb.x + xb.y) + (xb.z + xb.w);
        float q = fmaf(xa.x, xa.x, fmaf(xa.y, xa.y, fmaf(xa.z, xa.z, xa.w * xa.w)));
        q = fmaf(xb.x, xb.x, fmaf(xb.y, xb.y, fmaf(xb.z, xb.z, fmaf(xb.w, xb.w, q))));
#pragma unroll
        for (int off = 1; off < 64; off <<= 1) {
            s += __shfl_xor(s, off);
            q += __shfl_xor(q, off);
        }
        float mu = s * (1.0f / H);
        float var = q * (1.0f / H) - mu * mu;   // tanh outputs in [-1,1]: safe
        float inv = rsqrtf(var + 1e-5f);
        const float* gp = gamma + lane * 8;
        const float* bp = beta + lane * 8;
        float4 ga = *(const float4*)gp, gb = *(const float4*)(gp + 4);
        float4 ba = *(const float4*)bp, bb = *(const float4*)(bp + 4);
        float* o = out + (size_t)row * H + lane * 8;
        *(float4*)o = make_float4((xa.x - mu) * inv * ga.x + ba.x,
                                  (xa.y - mu) * inv * ga.y + ba.y,
                                  (xa.z - mu) * inv * ga.z + ba.z,
                                  (xa.w - mu) * inv * ga.w + ba.w);
        *(float4*)(o + 4) = make_float4((xb.x - mu) * inv * gb.x + bb.x,
                                        (xb.y - mu) * inv * gb.y + bb.y,
                                        (xb.z - mu) * inv * gb.z + bb.z,
                                        (xb.w - mu) * inv * gb.w + bb.w);
    }
}

extern "C" void kernel_launch(void* const* d_in, const int* in_sizes, int n_in,
                              void* d_out, int out_size, void* d_ws, size_t ws_size,
                              hipStream_t stream) {
    const float* query = (const float*)d_in[0];
    const float* enc   = (const float*)d_in[1];
    const int*   slen  = (const int*)d_in[2];
    const float* W_h   = (const float*)d_in[3];
    const float* W_s   = (const float*)d_in[4];
    const float* v     = (const float*)d_in[5];
    const float* W_out = (const float*)d_in[6];
    const float* b_out = (const float*)d_in[7];
    const float* gamma = (const float*)d_in[8];
    const float* beta  = (const float*)d_in[9];
    float* out = (float*)d_out;

    // ---- workspace map, non-aliased (d_ws = 256 MB) ----
    char* base = (char*)d_ws;
    short* qb     = (short*)(base + 0);          // 512K  bf16 query
    short* wsb    = (short*)(base + 524288);     // 512K  bf16 W_s
    short* whb    = (short*)(base + 1048576);    // 512K  bf16 W_h
    short* wob    = (short*)(base + 1572864);    // 1M    bf16 W_out
    short* eb     = (short*)(base + 2621440);    // 2M    bf16 enc
    float* qe     = (float*)(base + 4718592);    // 1M    f32 exp2(q_proj~)
    float* ke     = (float*)(base + 5767168);    // 4M    f32 exp2(k_proj~)
    float* scoreh = (float*)(base + 9961472);    // 4M    f32 score quarters
    short* attnb  = (short*)(base + 14155776);   // 512K  bf16 attn
    short* encT   = (short*)(base + 14680064);   // 2M    bf16 enc^T
    short* ctxb   = (short*)(base + 16777216);   // 512K  bf16 ctx
    float* pre    = (float*)(base + 17301504);   // 1M    f32 pre-LN

    void* args[] = {
        (void*)&query, (void*)&enc, (void*)&slen, (void*)&W_s, (void*)&W_h,
        (void*)&v, (void*)&W_out, (void*)&b_out, (void*)&gamma, (void*)&beta,
        (void*)&out,
        (void*)&qb, (void*)&wsb, (void*)&whb, (void*)&wob, (void*)&eb,
        (void*)&encT, (void*)&qe, (void*)&ke, (void*)&scoreh,
        (void*)&attnb, (void*)&ctxb, (void*)&pre
    };
    hipLaunchCooperativeKernel((void*)mega_kernel, dim3(512), dim3(256),
                               args, 0, stream);
}

// Round 12
// 81.868 us; speedup vs baseline: 5.5157x; 5.5157x over previous
//
#include <hip/hip_runtime.h>
#include <hip/hip_bf16.h>
#include <math.h>

#define B 4
#define T 128
#define S 512
#define H 512
// 2*log2(e): folds tanh's 2x and e->2 base change into the projection epilogue
#define QK_SCALE 2.8853900817779268f

// Hardware exp2 (v_exp_f32). Fallback = native exp path, never OCML-precise.
#if defined(__has_builtin)
#if __has_builtin(__builtin_amdgcn_exp2f)
#define EXP2F(x) __builtin_amdgcn_exp2f(x)
#else
#define EXP2F(x) __expf((x) * 0.6931471805599453f)
#endif
#else
#define EXP2F(x) __expf((x) * 0.6931471805599453f)
#endif

typedef __attribute__((ext_vector_type(8))) short bf16x8;
typedef __attribute__((ext_vector_type(4))) float f32x4;

__device__ __forceinline__ short f2b(float x) {   // f32 -> bf16 RNE
    unsigned int u = __float_as_uint(x);
    u += 0x7fffu + ((u >> 16) & 1u);
    return (short)(u >> 16);
}
__device__ __forceinline__ float blo(unsigned int u) {  // low bf16 -> f32
    return __uint_as_float(u << 16);
}
__device__ __forceinline__ float bhi(unsigned int u) {  // high bf16 -> f32
    return __uint_as_float(u & 0xffff0000u);
}
__device__ __forceinline__ float fast_tanh(float x) {
    float e = __expf(2.0f * x);
    float r = __builtin_amdgcn_rcpf(e + 1.0f);
    return 1.0f - 2.0f * r;
}

// ---- phase 1: cvt to bf16 (0..1151) + encT transpose (1152..2175) + Z zero (2176) ----
__global__ __launch_bounds__(256) void cvt_all(
    const float* __restrict__ q, const float* __restrict__ Ws,
    const float* __restrict__ Wh, const float* __restrict__ Wo,
    const float* __restrict__ enc, const int* __restrict__ slen,
    short* __restrict__ qb, short* __restrict__ wsb, short* __restrict__ whb,
    short* __restrict__ wob, short* __restrict__ eb, short* __restrict__ encT,
    float* __restrict__ Z) {
    const int bid = blockIdx.x;
    const int tid = threadIdx.x;
    if (bid == 2176) {   // Z normalizers zeroed fresh every call (replay-safe)
        Z[tid] = 0.f;
        Z[tid + 256] = 0.f;
        return;
    }
    if (bid >= 1152) {   // encT[b][h][s] = bf16(enc[b][s][h])
        __shared__ short tb[32][33];
        const int bid2 = bid - 1152;
        const int b = bid2 >> 8, s0 = ((bid2 >> 4) & 15) * 32, h0 = (bid2 & 15) * 32;
        if (s0 >= slen[b]) return;   // cols >= ceil32(L): attn exactly 0 there
        const int r = tid >> 3, c = (tid & 7) * 4;
        float4 a = *(const float4*)&enc[((size_t)(b * S + s0 + r)) * H + h0 + c];
        tb[c + 0][r] = f2b(a.x); tb[c + 1][r] = f2b(a.y);
        tb[c + 2][r] = f2b(a.z); tb[c + 3][r] = f2b(a.w);
        __syncthreads();
        ushort4 o = make_ushort4((unsigned short)tb[r][c], (unsigned short)tb[r][c + 1],
                                 (unsigned short)tb[r][c + 2], (unsigned short)tb[r][c + 3]);
        *(ushort4*)&encT[((size_t)(b * H + h0 + r)) * S + s0 + c] = o;
        return;
    }
    size_t i = ((size_t)bid * 256 + tid) * 8;
    const float* src; short* dst; size_t off;
    if (i < 262144)        { src = q;   dst = qb;  off = i; }
    else if (i < 524288)   { src = Ws;  dst = wsb; off = i - 262144; }
    else if (i < 786432)   { src = Wh;  dst = whb; off = i - 524288; }
    else if (i < 1310720)  { src = Wo;  dst = wob; off = i - 786432; }
    else                   { src = enc; dst = eb;  off = i - 1310720; }
    float4 a = *(const float4*)(src + off);
    float4 b = *(const float4*)(src + off + 4);
    ushort4 o0 = make_ushort4((unsigned short)f2b(a.x), (unsigned short)f2b(a.y),
                              (unsigned short)f2b(a.z), (unsigned short)f2b(a.w));
    ushort4 o1 = make_ushort4((unsigned short)f2b(b.x), (unsigned short)f2b(b.y),
                              (unsigned short)f2b(b.z), (unsigned short)f2b(b.w));
    *(ushort4*)(dst + off) = o0;
    *(ushort4*)(dst + off + 4) = o1;
}

#define MFMA4(APTR0, APTR1, BPTR0, BPTR1, KOFF)                                  \
    {                                                                            \
        bf16x8 a0 = *(const bf16x8*)((APTR0) + (KOFF));                          \
        bf16x8 a1 = *(const bf16x8*)((APTR1) + (KOFF));                          \
        bf16x8 b0 = *(const bf16x8*)((BPTR0) + (KOFF));                          \
        bf16x8 b1 = *(const bf16x8*)((BPTR1) + (KOFF));                          \
        acc00 = __builtin_amdgcn_mfma_f32_16x16x32_bf16(a0, b0, acc00, 0, 0, 0); \
        acc01 = __builtin_amdgcn_mfma_f32_16x16x32_bf16(a0, b1, acc01, 0, 0, 0); \
        acc10 = __builtin_amdgcn_mfma_f32_16x16x32_bf16(a1, b0, acc10, 0, 0, 0); \
        acc11 = __builtin_amdgcn_mfma_f32_16x16x32_bf16(a1, b1, acc11, 0, 0, 0); \
    }

// ---- phase 2: projections, Eq/Ek = bf16(exp2(GEMM * 2log2e)) ----
// exp factorization: exp2(q~+k~) = Eq*Ek -> score needs no exp per element.
__global__ __launch_bounds__(64) void mfma_proj(
    const short* __restrict__ qb, const short* __restrict__ eb,
    const short* __restrict__ wsb, const short* __restrict__ whb,
    const int* __restrict__ slen, short* __restrict__ qeb, short* __restrict__ keb) {
    const int lane = threadIdx.x;
    const int r = lane & 15, kb = lane >> 4;
    const int n0 = blockIdx.x * 32;
    const int m0 = blockIdx.y * 32;
    const short* A; const short* W; short* C;
    if (m0 < 512) { A = qb + (size_t)m0 * H; W = wsb; C = qeb + (size_t)m0 * H; }
    else {
        const int row = m0 - 512;
        if ((row & 511) >= slen[row >> 9]) return;   // fully-masked k-tile
        A = eb + (size_t)row * H; W = whb; C = keb + (size_t)row * H;
    }
    const short* a0p = A + (size_t)r * H + kb * 8;
    const short* a1p = a0p + 16 * H;
    const short* b0p = W + (size_t)(n0 + r) * H + kb * 8;
    const short* b1p = b0p + 16 * H;
    f32x4 acc00 = {0,0,0,0}, acc01 = {0,0,0,0}, acc10 = {0,0,0,0}, acc11 = {0,0,0,0};
#pragma unroll 4
    for (int k = 0; k < H; k += 32) MFMA4(a0p, a1p, b0p, b1p, k)
    const int cr = kb * 4, cc = r;
#pragma unroll
    for (int g = 0; g < 4; ++g) {
        C[(size_t)(cr + g) * H + n0 + cc]           = f2b(EXP2F(acc00[g] * QK_SCALE));
        C[(size_t)(cr + g) * H + n0 + 16 + cc]      = f2b(EXP2F(acc01[g] * QK_SCALE));
        C[(size_t)(16 + cr + g) * H + n0 + cc]      = f2b(EXP2F(acc10[g] * QK_SCALE));
        C[(size_t)(16 + cr + g) * H + n0 + 16 + cc] = f2b(EXP2F(acc11[g] * QK_SCALE));
    }
}

// ---- phase 3: full-h score -> UNNORMALIZED attn U = bf16(exp(score')) + Z atomics ----
// score' = -sum_h 2 v[h] rcp(Eq*Ek + 1); |score'| <= 2*sum|v| ~ 8 -> exp safe
// without max-shift. softmax stage eliminated; ctx divides by Z later.
__global__ __launch_bounds__(64) void score_v5(
    const short* __restrict__ qeb, const short* __restrict__ keb,
    const float* __restrict__ v, const int* __restrict__ slen,
    short* __restrict__ attnb, float* __restrict__ Z) {
    const int b = blockIdx.z;
    const int L = slen[b];
    const int Keff = min(S, (L + 31) & ~31);
    const int sbase = blockIdx.x * 16;
    if (sbase >= Keff) return;
    const int tbase = blockIdx.y * 8;
    const int lane = threadIdx.x;
    const int t = lane >> 3, s2 = (lane & 7) * 2;
    const int row = b * T + tbase + t;
    unsigned int* op = (unsigned int*)(attnb + (size_t)row * S + sbase + s2);
    if (sbase >= L) {        // tile inside [L, Keff): exact zeros, no Z add
        *op = 0u;
        return;
    }
    // bf16 LDS tiles: 27 KB/block -> ~5 blocks/CU. Row stride 520 shorts =
    // 1040 B -> row r base bank 4r&31: q rows 0..7 distinct banks; k even/odd
    // row sets are 2-way (free).
    __shared__ __align__(16) short qs[8][520];
    __shared__ __align__(16) short ks[16][520];
    __shared__ __align__(16) float vsh[512];
    {
        const int r = lane >> 3, c = (lane & 7) * 64;
        const short* qsrc = qeb + (size_t)(b * T + tbase + r) * H + c;
        const short* k0src = keb + (size_t)(b * S + sbase + r) * H + c;
        const short* k1src = k0src + 8 * H;
#pragma unroll
        for (int j = 0; j < 8; ++j) {
            *(bf16x8*)&qs[r][c + j * 8] = *(const bf16x8*)(qsrc + j * 8);
            *(bf16x8*)&ks[r][c + j * 8] = *(const bf16x8*)(k0src + j * 8);
            *(bf16x8*)&ks[8 + r][c + j * 8] = *(const bf16x8*)(k1src + j * 8);
        }
        float4 v0 = *(const float4*)&v[lane * 8];
        float4 v1 = *(const float4*)&v[lane * 8 + 4];
        *(float4*)&vsh[lane * 8] = make_float4(-2.f * v0.x, -2.f * v0.y, -2.f * v0.z, -2.f * v0.w);
        *(float4*)&vsh[lane * 8 + 4] = make_float4(-2.f * v1.x, -2.f * v1.y, -2.f * v1.z, -2.f * v1.w);
    }
    __syncthreads();
    const unsigned int* qrow = (const unsigned int*)&qs[t][0];
    const unsigned int* k0r = (const unsigned int*)&ks[s2][0];
    const unsigned int* k1r = (const unsigned int*)&ks[s2 + 1][0];
    float a0 = 0.f, a1 = 0.f, c0 = 0.f, c1 = 0.f;
#pragma unroll 4
    for (int i = 0; i < 256; i += 2) {   // 4 h x 2 s per iter
        uint2 qu = *(const uint2*)&qrow[i];
        uint2 k0u = *(const uint2*)&k0r[i];
        uint2 k1u = *(const uint2*)&k1r[i];
        float4 vv = *(const float4*)&vsh[i * 2];
        a0 = fmaf(vv.x, __builtin_amdgcn_rcpf(fmaf(blo(qu.x), blo(k0u.x), 1.f)), a0);
        c0 = fmaf(vv.x, __builtin_amdgcn_rcpf(fmaf(blo(qu.x), blo(k1u.x), 1.f)), c0);
        a1 = fmaf(vv.y, __builtin_amdgcn_rcpf(fmaf(bhi(qu.x), bhi(k0u.x), 1.f)), a1);
        c1 = fmaf(vv.y, __builtin_amdgcn_rcpf(fmaf(bhi(qu.x), bhi(k1u.x), 1.f)), c1);
        a0 = fmaf(vv.z, __builtin_amdgcn_rcpf(fmaf(blo(qu.y), blo(k0u.y), 1.f)), a0);
        c0 = fmaf(vv.z, __builtin_amdgcn_rcpf(fmaf(blo(qu.y), blo(k1u.y), 1.f)), c0);
        a1 = fmaf(vv.w, __builtin_amdgcn_rcpf(fmaf(bhi(qu.y), bhi(k0u.y), 1.f)), a1);
        c1 = fmaf(vv.w, __builtin_amdgcn_rcpf(fmaf(bhi(qu.y), bhi(k1u.y), 1.f)), c1);
    }
    float ex0 = __expf(a0 + a1);
    float ex1 = __expf(c0 + c1);
    if (sbase + s2 >= L) ex0 = 0.f;        // straddle-tile masked columns
    if (sbase + s2 + 1 >= L) ex1 = 0.f;
    unsigned int pack = (unsigned int)(unsigned short)f2b(ex0) |
                        ((unsigned int)(unsigned short)f2b(ex1) << 16);
    *op = pack;
    float zs = ex0 + ex1;                   // row partial: 8 lanes share row t
    zs += __shfl_xor(zs, 1);
    zs += __shfl_xor(zs, 2);
    zs += __shfl_xor(zs, 4);
    if ((lane & 7) == 0) atomicAdd(&Z[row], zs);
}

// ---- phase 4: ctx = (U @ enc) / Z   (K capped at ceil32(L); masked U == 0) ----
__global__ __launch_bounds__(64) void mfma_ctx(
    const short* __restrict__ attnb, const short* __restrict__ encT,
    const int* __restrict__ slen, const float* __restrict__ Z,
    short* __restrict__ ctxb) {
    const int b = blockIdx.z;
    const int L = slen[b];
    const int Keff = min(S, (L + 31) & ~31);
    const int lane = threadIdx.x;
    const int r = lane & 15, kb = lane >> 4;
    const int m0 = blockIdx.y * 32;
    const int n0 = blockIdx.x * 32;
    const short* A = attnb + (size_t)(b * T + m0) * S;
    const short* Bp = encT + (size_t)b * H * S;
    const short* a0p = A + (size_t)r * S + kb * 8;
    const short* a1p = a0p + 16 * S;
    const short* b0p = Bp + (size_t)(n0 + r) * S + kb * 8;
    const short* b1p = b0p + 16 * S;
    f32x4 acc00 = {0,0,0,0}, acc01 = {0,0,0,0}, acc10 = {0,0,0,0}, acc11 = {0,0,0,0};
#pragma unroll 2
    for (int k = 0; k < Keff; k += 32) MFMA4(a0p, a1p, b0p, b1p, k)
    const int cr = kb * 4, cc = r;
#pragma unroll
    for (int g = 0; g < 4; ++g) {
        const int gr0 = b * T + m0 + cr + g;
        const int gr1 = gr0 + 16;
        float iz0 = __builtin_amdgcn_rcpf(Z[gr0]);
        float iz1 = __builtin_amdgcn_rcpf(Z[gr1]);
        size_t row0 = (size_t)gr0 * H;
        size_t row1 = (size_t)gr1 * H;
        ctxb[row0 + n0 + cc]      = f2b(acc00[g] * iz0);
        ctxb[row0 + n0 + 16 + cc] = f2b(acc01[g] * iz0);
        ctxb[row1 + n0 + cc]      = f2b(acc10[g] * iz1);
        ctxb[row1 + n0 + 16 + cc] = f2b(acc11[g] * iz1);
    }
}

// ---- phase 5: pre = tanh([ctx|query] @ W_out^T + b)  (all-bf16 operands) ----
__global__ __launch_bounds__(64) void mfma_out(
    const short* __restrict__ ctxb, const short* __restrict__ qb,
    const short* __restrict__ wob, const float* __restrict__ bias,
    float* __restrict__ pre) {
    const int lane = threadIdx.x;
    const int r = lane & 15, kb = lane >> 4;
    const int m0 = blockIdx.y * 32, n0 = blockIdx.x * 32;
    f32x4 acc00 = {0,0,0,0}, acc01 = {0,0,0,0}, acc10 = {0,0,0,0}, acc11 = {0,0,0,0};
    const short* b0p = wob + (size_t)(n0 + r) * (2 * H) + kb * 8;
    const short* b1p = b0p + 16 * (2 * H);
    {
        const short* a0p = ctxb + (size_t)(m0 + r) * H + kb * 8;
        const short* a1p = a0p + 16 * H;
#pragma unroll 4
        for (int k = 0; k < H; k += 32) MFMA4(a0p, a1p, b0p, b1p, k)
    }
    {
        const short* a0p = qb + (size_t)(m0 + r) * H + kb * 8;
        const short* a1p = a0p + 16 * H;
        const short* c0p = b0p + H;
        const short* c1p = b1p + H;
#pragma unroll 4
        for (int k = 0; k < H; k += 32) MFMA4(a0p, a1p, c0p, c1p, k)
    }
    const int cr = kb * 4, cc = r;
    float bn0 = bias[n0 + cc], bn1 = bias[n0 + 16 + cc];
#pragma unroll
    for (int g = 0; g < 4; ++g) {
        size_t row0 = (size_t)(m0 + cr + g) * H;
        size_t row1 = (size_t)(m0 + 16 + cr + g) * H;
        pre[row0 + n0 + cc]      = fast_tanh(acc00[g] + bn0);
        pre[row0 + n0 + 16 + cc] = fast_tanh(acc01[g] + bn1);
        pre[row1 + n0 + cc]      = fast_tanh(acc10[g] + bn0);
        pre[row1 + n0 + 16 + cc] = fast_tanh(acc11[g] + bn1);
    }
}

// ---- phase 6: per-row LayerNorm ----
__global__ __launch_bounds__(256) void ln_out(
    const float* __restrict__ X, const float* __restrict__ gamma,
    const float* __restrict__ beta, float* __restrict__ out) {
    __shared__ float red[8];
    const int r = blockIdx.x;
    const int tid = threadIdx.x;
    const int lane = tid & 63, wv = tid >> 6;
    const float* x = X + (size_t)r * H;
    float x0 = x[tid], x1 = x[tid + 256];
    float s = x0 + x1;
#pragma unroll
    for (int off = 32; off > 0; off >>= 1) s += __shfl_down(s, off);
    if (lane == 0) red[wv] = s;
    __syncthreads();
    float mu = (red[0] + red[1] + red[2] + red[3]) * (1.0f / H);
    float d0 = x0 - mu, d1 = x1 - mu;
    float vsum = d0 * d0 + d1 * d1;
#pragma unroll
    for (int off = 32; off > 0; off >>= 1) vsum += __shfl_down(vsum, off);
    if (lane == 0) red[4 + wv] = vsum;
    __syncthreads();
    float var = (red[4] + red[5] + red[6] + red[7]) * (1.0f / H);
    float inv = rsqrtf(var + 1e-5f);
    out[(size_t)r * H + tid] = d0 * inv * gamma[tid] + beta[tid];
    out[(size_t)r * H + tid + 256] = d1 * inv * gamma[tid + 256] + beta[tid + 256];
}

extern "C" void kernel_launch(void* const* d_in, const int* in_sizes, int n_in,
                              void* d_out, int out_size, void* d_ws, size_t ws_size,
                              hipStream_t stream) {
    const float* query = (const float*)d_in[0];
    const float* enc   = (const float*)d_in[1];
    const int*   slen  = (const int*)d_in[2];
    const float* W_h   = (const float*)d_in[3];
    const float* W_s   = (const float*)d_in[4];
    const float* v     = (const float*)d_in[5];
    const float* W_out = (const float*)d_in[6];
    const float* b_out = (const float*)d_in[7];
    const float* gamma = (const float*)d_in[8];
    const float* beta  = (const float*)d_in[9];
    float* out = (float*)d_out;

    // ---- workspace map, non-aliased (d_ws = 256 MB) ----
    char* base = (char*)d_ws;
    short* qb    = (short*)(base + 0);          // 512K  bf16 query
    short* wsb   = (short*)(base + 524288);     // 512K  bf16 W_s
    short* whb   = (short*)(base + 1048576);    // 512K  bf16 W_h
    short* wob   = (short*)(base + 1572864);    // 1M    bf16 W_out
    short* eb    = (short*)(base + 2621440);    // 2M    bf16 enc
    short* qeb   = (short*)(base + 4718592);    // 512K  bf16 exp2(q_proj~)
    short* keb   = (short*)(base + 5242880);    // 2M    bf16 exp2(k_proj~)
    short* attnb = (short*)(base + 7340032);    // 512K  bf16 unnormalized attn U
    short* encT  = (short*)(base + 7864320);    // 2M    bf16 enc^T
    short* ctxb  = (short*)(base + 9961472);    // 512K  bf16 ctx
    float* pre   = (float*)(base + 10485760);   // 1M    f32 pre-LN
    float* Z     = (float*)(base + 11534336);   // 2K    f32 row normalizers

    // cvt (1152) + encT (1024, masked tiles skipped) + Z zero (1)
    cvt_all<<<dim3(2177), dim3(256), 0, stream>>>(query, W_s, W_h, W_out, enc, slen,
                                                  qb, wsb, whb, wob, eb, encT, Z);
    mfma_proj<<<dim3(16, 80), dim3(64), 0, stream>>>(qb, eb, wsb, whb, slen, qeb, keb);
    // full-h score -> U + Z: grid (s-tiles=32, t-tiles=16, b=4)
    score_v5<<<dim3(32, 16, 4), dim3(64), 0, stream>>>(qeb, keb, v, slen, attnb, Z);
    mfma_ctx<<<dim3(16, 4, 4), dim3(64), 0, stream>>>(attnb, encT, slen, Z, ctxb);
    mfma_out<<<dim3(16, 16), dim3(64), 0, stream>>>(ctxb, qb, wob, b_out, pre);
    ln_out<<<dim3(B * T), dim3(256), 0, stream>>>(pre, gamma, beta, out);
}

// Round 13
// 65.156 us; speedup vs baseline: 6.9304x; 1.2565x over previous
//
#include <hip/hip_runtime.h>
#include <hip/hip_bf16.h>
#include <math.h>

#define B 4
#define T 128
#define S 512
#define H 512
// 2*log2(e): folds tanh's 2x and e->2 base change into the projection epilogue
#define QK_SCALE 2.8853900817779268f

// Hardware exp2 (v_exp_f32). Fallback = native exp path, never OCML-precise.
#if defined(__has_builtin)
#if __has_builtin(__builtin_amdgcn_exp2f)
#define EXP2F(x) __builtin_amdgcn_exp2f(x)
#else
#define EXP2F(x) __expf((x) * 0.6931471805599453f)
#endif
#else
#define EXP2F(x) __expf((x) * 0.6931471805599453f)
#endif

typedef __attribute__((ext_vector_type(8))) short bf16x8;
typedef __attribute__((ext_vector_type(4))) float f32x4;

__device__ __forceinline__ short f2b(float x) {   // f32 -> bf16 RNE
    unsigned int u = __float_as_uint(x);
    u += 0x7fffu + ((u >> 16) & 1u);
    return (short)(u >> 16);
}
__device__ __forceinline__ float fast_tanh(float x) {
    float e = __expf(2.0f * x);
    float r = __builtin_amdgcn_rcpf(e + 1.0f);
    return 1.0f - 2.0f * r;
}

// ---- phase 1: cvt inputs to bf16 (1152 blocks; no transpose needed anymore) ----
__global__ __launch_bounds__(256) void cvt_all(
    const float* __restrict__ q, const float* __restrict__ Ws,
    const float* __restrict__ Wh, const float* __restrict__ Wo,
    const float* __restrict__ enc,
    short* __restrict__ qb, short* __restrict__ wsb, short* __restrict__ whb,
    short* __restrict__ wob, short* __restrict__ eb) {
    size_t i = ((size_t)blockIdx.x * 256 + threadIdx.x) * 8;
    const float* src; short* dst; size_t off;
    if (i < 262144)        { src = q;   dst = qb;  off = i; }
    else if (i < 524288)   { src = Ws;  dst = wsb; off = i - 262144; }
    else if (i < 786432)   { src = Wh;  dst = whb; off = i - 524288; }
    else if (i < 1310720)  { src = Wo;  dst = wob; off = i - 786432; }
    else                   { src = enc; dst = eb;  off = i - 1310720; }
    float4 a = *(const float4*)(src + off);
    float4 b = *(const float4*)(src + off + 4);
    ushort4 o0 = make_ushort4((unsigned short)f2b(a.x), (unsigned short)f2b(a.y),
                              (unsigned short)f2b(a.z), (unsigned short)f2b(a.w));
    ushort4 o1 = make_ushort4((unsigned short)f2b(b.x), (unsigned short)f2b(b.y),
                              (unsigned short)f2b(b.z), (unsigned short)f2b(b.w));
    *(ushort4*)(dst + off) = o0;
    *(ushort4*)(dst + off + 4) = o1;
}

// ---- phase 2: mega wave-GEMM: 2560 one-wave 32x32 jobs ----
//   jobs [0,256):     Eq = exp2(q@Ws^T * QKS)            -> qe   (f32)
//   jobs [256,1280):  Ek = exp2(enc@Wh^T * QKS)          -> ke   (f32)  [masked tiles skip]
//   jobs [1280,2304): EWT[b][o][s] = bf16(Wo1@enc_b^T)   -> ewt  (bf16) [masked s-tiles skip]
//   jobs [2304,2560): QW = q@Wo2^T                       -> qw   (f32)
// Associativity: ((U/Z)@enc)@Wo1 == (U@EWT)/Z -> ctx stage & encT eliminated.
__global__ __launch_bounds__(64) void proj_mega(
    const short* __restrict__ qb, const short* __restrict__ eb,
    const short* __restrict__ wsb, const short* __restrict__ whb,
    const short* __restrict__ wob, const int* __restrict__ slen,
    float* __restrict__ qe, float* __restrict__ ke,
    short* __restrict__ ewt, float* __restrict__ qw) {
    const int job = blockIdx.x;
    const int lane = threadIdx.x;
    const int r = lane & 15, kb = lane >> 4;
    const short* A; int lda;
    const short* W; int ldw;
    int epi;            // 0 = f32 exp2(acc*QKS), 1 = bf16 plain, 2 = f32 plain
    float* Cf = nullptr; short* Cb = nullptr; int ldc;
    if (job < 256) {
        const int m0 = (job >> 4) * 32, n0 = (job & 15) * 32;
        A = qb + (size_t)m0 * H; lda = H;
        W = wsb + (size_t)n0 * H; ldw = H;
        Cf = qe + (size_t)m0 * H + n0; ldc = H; epi = 0;
    } else if (job < 1280) {
        const int j = job - 256;
        const int m0 = (j >> 4) * 32, n0 = (j & 15) * 32;
        if ((m0 & 511) >= slen[m0 >> 9]) return;   // fully-masked k-tile
        A = eb + (size_t)m0 * H; lda = H;
        W = whb + (size_t)n0 * H; ldw = H;
        Cf = ke + (size_t)m0 * H + n0; ldc = H; epi = 0;
    } else if (job < 2304) {
        const int j = job - 1280;
        const int b = j >> 8;
        const int m0 = ((j >> 4) & 15) * 32;       // o
        const int n0 = (j & 15) * 32;              // s
        if (n0 >= slen[b]) return;                 // U==0 there, never read
        A = wob + (size_t)m0 * (2 * H); lda = 2 * H;              // Wo1 rows
        W = eb + ((size_t)b * S + n0) * H; ldw = H;               // enc_b rows
        Cb = ewt + (size_t)b * H * S + (size_t)m0 * S + n0; ldc = S; epi = 1;
    } else {
        const int j = job - 2304;
        const int m0 = (j >> 4) * 32, n0 = (j & 15) * 32;
        A = qb + (size_t)m0 * H; lda = H;
        W = wob + (size_t)n0 * (2 * H) + H; ldw = 2 * H;          // Wo2 rows
        Cf = qw + (size_t)m0 * H + n0; ldc = H; epi = 2;
    }
    const short* a0p = A + (size_t)r * lda + kb * 8;
    const short* a1p = a0p + (size_t)16 * lda;
    const short* b0p = W + (size_t)r * ldw + kb * 8;
    const short* b1p = b0p + (size_t)16 * ldw;
    f32x4 acc00 = {0,0,0,0}, acc01 = {0,0,0,0}, acc10 = {0,0,0,0}, acc11 = {0,0,0,0};
#pragma unroll 4
    for (int k = 0; k < H; k += 32) {
        bf16x8 a0 = *(const bf16x8*)(a0p + k);
        bf16x8 a1 = *(const bf16x8*)(a1p + k);
        bf16x8 b0 = *(const bf16x8*)(b0p + k);
        bf16x8 b1 = *(const bf16x8*)(b1p + k);
        acc00 = __builtin_amdgcn_mfma_f32_16x16x32_bf16(a0, b0, acc00, 0, 0, 0);
        acc01 = __builtin_amdgcn_mfma_f32_16x16x32_bf16(a0, b1, acc01, 0, 0, 0);
        acc10 = __builtin_amdgcn_mfma_f32_16x16x32_bf16(a1, b0, acc10, 0, 0, 0);
        acc11 = __builtin_amdgcn_mfma_f32_16x16x32_bf16(a1, b1, acc11, 0, 0, 0);
    }
    const int cr = kb * 4, cc = r;
    if (epi == 0) {
#pragma unroll
        for (int g = 0; g < 4; ++g) {
            Cf[(size_t)(cr + g) * ldc + cc]           = EXP2F(acc00[g] * QK_SCALE);
            Cf[(size_t)(cr + g) * ldc + 16 + cc]      = EXP2F(acc01[g] * QK_SCALE);
            Cf[(size_t)(16 + cr + g) * ldc + cc]      = EXP2F(acc10[g] * QK_SCALE);
            Cf[(size_t)(16 + cr + g) * ldc + 16 + cc] = EXP2F(acc11[g] * QK_SCALE);
        }
    } else if (epi == 1) {
#pragma unroll
        for (int g = 0; g < 4; ++g) {
            Cb[(size_t)(cr + g) * ldc + cc]           = f2b(acc00[g]);
            Cb[(size_t)(cr + g) * ldc + 16 + cc]      = f2b(acc01[g]);
            Cb[(size_t)(16 + cr + g) * ldc + cc]      = f2b(acc10[g]);
            Cb[(size_t)(16 + cr + g) * ldc + 16 + cc] = f2b(acc11[g]);
        }
    } else {
#pragma unroll
        for (int g = 0; g < 4; ++g) {
            Cf[(size_t)(cr + g) * ldc + cc]           = acc00[g];
            Cf[(size_t)(cr + g) * ldc + 16 + cc]      = acc01[g];
            Cf[(size_t)(16 + cr + g) * ldc + cc]      = acc10[g];
            Cf[(size_t)(16 + cr + g) * ldc + 16 + cc] = acc11[g];
        }
    }
}

// ---- phase 3: partial score over one h-quarter (128 h), 8t x 16s per wave ----
// scoreh[qt][b*T+t][s] = -sum_h 2 v[h] * rcp(Eq[t,h]*Ek[s,h] + 1)   (R9 proven)
__global__ __launch_bounds__(64) void score_v4(
    const float* __restrict__ qe, const float* __restrict__ ke,
    const float* __restrict__ v, const int* __restrict__ slen,
    float* __restrict__ scoreh) {
    const int qt = blockIdx.z & 3;
    const int b = blockIdx.z >> 2;
    const int L = slen[b];
    const int sbase = blockIdx.x * 16;
    if (sbase >= L) return;
    const int tbase = blockIdx.y * 8;
    const int hbase = qt * 128;
    __shared__ __align__(16) float qs[8][132];
    __shared__ __align__(16) float ks[16][132];
    __shared__ __align__(16) float vsh[128];
    const int lane = threadIdx.x;
    {   // staging: q row r=lane>>3 (4 float4), k rows r and r+8 (8 float4)
        const int r = lane >> 3, c = (lane & 7) * 16;
        const float* qsrc = qe + (size_t)(b * T + tbase + r) * H + hbase + c;
        const float* k0src = ke + (size_t)(b * S + sbase + r) * H + hbase + c;
        const float* k1src = k0src + 8 * H;
#pragma unroll
        for (int j = 0; j < 4; ++j) {
            *(float4*)&qs[r][c + j * 4] = *(const float4*)(qsrc + j * 4);
            *(float4*)&ks[r][c + j * 4] = *(const float4*)(k0src + j * 4);
            *(float4*)&ks[8 + r][c + j * 4] = *(const float4*)(k1src + j * 4);
        }
        float2 vv = *(const float2*)&v[hbase + lane * 2];
        *(float2*)&vsh[lane * 2] = make_float2(-2.f * vv.x, -2.f * vv.y);
    }
    __syncthreads();
    const int t = lane >> 3, s0 = (lane & 7) * 2;
    const float* qrow = &qs[t][0];
    const float* k0r = &ks[s0][0];
    const float* k1r = &ks[s0 + 1][0];
    float a0 = 0.f, a1 = 0.f, c0 = 0.f, c1 = 0.f;
#pragma unroll 2
    for (int i = 0; i < 128; i += 4) {   // per elem: fma, rcp, fma
        float4 q4 = *(const float4*)&qrow[i];
        float4 ka = *(const float4*)&k0r[i];
        float4 kb = *(const float4*)&k1r[i];
        float4 v4 = *(const float4*)&vsh[i];
        a0 = fmaf(v4.x, __builtin_amdgcn_rcpf(fmaf(q4.x, ka.x, 1.f)), a0);
        c0 = fmaf(v4.x, __builtin_amdgcn_rcpf(fmaf(q4.x, kb.x, 1.f)), c0);
        a1 = fmaf(v4.y, __builtin_amdgcn_rcpf(fmaf(q4.y, ka.y, 1.f)), a1);
        c1 = fmaf(v4.y, __builtin_amdgcn_rcpf(fmaf(q4.y, kb.y, 1.f)), c1);
        a0 = fmaf(v4.z, __builtin_amdgcn_rcpf(fmaf(q4.z, ka.z, 1.f)), a0);
        c0 = fmaf(v4.z, __builtin_amdgcn_rcpf(fmaf(q4.z, kb.z, 1.f)), c0);
        a1 = fmaf(v4.w, __builtin_amdgcn_rcpf(fmaf(q4.w, ka.w, 1.f)), a1);
        c1 = fmaf(v4.w, __builtin_amdgcn_rcpf(fmaf(q4.w, kb.w, 1.f)), c1);
    }
    *(float2*)&scoreh[((size_t)qt * (B * T) + b * T + tbase + t) * S + sbase + s0] =
        make_float2(a0 + a1, c0 + c1);
}

// ---- phase 4: combine quarters -> U = bf16(exp(score')) + Z[row] ----
// |score'| <= 2*sum|v| ~ 8 -> exp is overflow-safe WITHOUT max-shift.
// 4 rows per 256-thread block, one wave per row; Z stored directly (no atomics).
__global__ __launch_bounds__(256) void combine_k(
    const float* __restrict__ scoreh, const int* __restrict__ slen,
    short* __restrict__ U, float* __restrict__ Z) {
    const int row = blockIdx.x * 4 + (threadIdx.x >> 6);
    const int lane = threadIdx.x & 63;
    const int L = slen[row >> 7];
    const size_t sl = (size_t)(B * T) * S;
    const float* p = scoreh + (size_t)row * S + lane * 8;
    float e[8];
    float sm = 0.f;
#pragma unroll
    for (int j = 0; j < 2; ++j) {
        float4 q0 = *(const float4*)(p + j * 4);
        float4 q1 = *(const float4*)(p + sl + j * 4);
        float4 q2 = *(const float4*)(p + 2 * sl + j * 4);
        float4 q3 = *(const float4*)(p + 3 * sl + j * 4);
        e[j * 4 + 0] = __expf(q0.x + q1.x + q2.x + q3.x);
        e[j * 4 + 1] = __expf(q0.y + q1.y + q2.y + q3.y);
        e[j * 4 + 2] = __expf(q0.z + q1.z + q2.z + q3.z);
        e[j * 4 + 3] = __expf(q0.w + q1.w + q2.w + q3.w);
    }
    const int cbase = lane * 8;
#pragma unroll
    for (int j = 0; j < 8; ++j) {
        if (cbase + j >= L) e[j] = 0.f;   // masked (incl. straddle garbage)
        sm += e[j];
    }
#pragma unroll
    for (int off = 1; off < 64; off <<= 1) sm += __shfl_xor(sm, off);
    if (lane == 0) Z[row] = sm;
    short* o = U + (size_t)row * S + cbase;
    ushort4 u0 = make_ushort4((unsigned short)f2b(e[0]), (unsigned short)f2b(e[1]),
                              (unsigned short)f2b(e[2]), (unsigned short)f2b(e[3]));
    ushort4 u1 = make_ushort4((unsigned short)f2b(e[4]), (unsigned short)f2b(e[5]),
                              (unsigned short)f2b(e[6]), (unsigned short)f2b(e[7]));
    *(ushort4*)o = u0;
    *(ushort4*)(o + 4) = u1;
}

// ---- phase 5: pre = tanh((U @ EWT)/Z + QW + bias)  (K capped at ceil32(L)) ----
__global__ __launch_bounds__(64) void mfma_out2(
    const short* __restrict__ U, const short* __restrict__ ewt,
    const float* __restrict__ qw, const float* __restrict__ Z,
    const int* __restrict__ slen, const float* __restrict__ bias,
    float* __restrict__ pre) {
    const int lane = threadIdx.x;
    const int r = lane & 15, kb = lane >> 4;
    const int m0 = blockIdx.y * 32;        // t-rows
    const int n0 = blockIdx.x * 32;        // o-cols
    const int b = m0 >> 7;
    const int L = slen[b];
    const int Keff = min(S, (L + 31) & ~31);
    const short* A = U + (size_t)m0 * S;
    const short* Bp = ewt + (size_t)b * H * S;
    const short* a0p = A + (size_t)r * S + kb * 8;
    const short* a1p = a0p + 16 * S;
    const short* b0p = Bp + (size_t)(n0 + r) * S + kb * 8;
    const short* b1p = b0p + 16 * S;
    f32x4 acc00 = {0,0,0,0}, acc01 = {0,0,0,0}, acc10 = {0,0,0,0}, acc11 = {0,0,0,0};
#pragma unroll 2
    for (int k = 0; k < Keff; k += 32) {
        bf16x8 a0 = *(const bf16x8*)(a0p + k);
        bf16x8 a1 = *(const bf16x8*)(a1p + k);
        bf16x8 b0 = *(const bf16x8*)(b0p + k);
        bf16x8 b1 = *(const bf16x8*)(b1p + k);
        acc00 = __builtin_amdgcn_mfma_f32_16x16x32_bf16(a0, b0, acc00, 0, 0, 0);
        acc01 = __builtin_amdgcn_mfma_f32_16x16x32_bf16(a0, b1, acc01, 0, 0, 0);
        acc10 = __builtin_amdgcn_mfma_f32_16x16x32_bf16(a1, b0, acc10, 0, 0, 0);
        acc11 = __builtin_amdgcn_mfma_f32_16x16x32_bf16(a1, b1, acc11, 0, 0, 0);
    }
    const int cr = kb * 4, cc = r;
    float bn0 = bias[n0 + cc], bn1 = bias[n0 + 16 + cc];
#pragma unroll
    for (int g = 0; g < 4; ++g) {
        const int gr0 = m0 + cr + g;
        const int gr1 = gr0 + 16;
        float iz0 = __builtin_amdgcn_rcpf(Z[gr0]);
        float iz1 = __builtin_amdgcn_rcpf(Z[gr1]);
        size_t row0 = (size_t)gr0 * H;
        size_t row1 = (size_t)gr1 * H;
        pre[row0 + n0 + cc]      = fast_tanh(fmaf(acc00[g], iz0, qw[row0 + n0 + cc]) + bn0);
        pre[row0 + n0 + 16 + cc] = fast_tanh(fmaf(acc01[g], iz0, qw[row0 + n0 + 16 + cc]) + bn1);
        pre[row1 + n0 + cc]      = fast_tanh(fmaf(acc10[g], iz1, qw[row1 + n0 + cc]) + bn0);
        pre[row1 + n0 + 16 + cc] = fast_tanh(fmaf(acc11[g], iz1, qw[row1 + n0 + 16 + cc]) + bn1);
    }
}

// ---- phase 6: per-row LayerNorm ----
__global__ __launch_bounds__(256) void ln_out(
    const float* __restrict__ X, const float* __restrict__ gamma,
    const float* __restrict__ beta, float* __restrict__ out) {
    __shared__ float red[8];
    const int r = blockIdx.x;
    const int tid = threadIdx.x;
    const int lane = tid & 63, wv = tid >> 6;
    const float* x = X + (size_t)r * H;
    float x0 = x[tid], x1 = x[tid + 256];
    float s = x0 + x1;
#pragma unroll
    for (int off = 32; off > 0; off >>= 1) s += __shfl_down(s, off);
    if (lane == 0) red[wv] = s;
    __syncthreads();
    float mu = (red[0] + red[1] + red[2] + red[3]) * (1.0f / H);
    float d0 = x0 - mu, d1 = x1 - mu;
    float vsum = d0 * d0 + d1 * d1;
#pragma unroll
    for (int off = 32; off > 0; off >>= 1) vsum += __shfl_down(vsum, off);
    if (lane == 0) red[4 + wv] = vsum;
    __syncthreads();
    float var = (red[4] + red[5] + red[6] + red[7]) * (1.0f / H);
    float inv = rsqrtf(var + 1e-5f);
    out[(size_t)r * H + tid] = d0 * inv * gamma[tid] + beta[tid];
    out[(size_t)r * H + tid + 256] = d1 * inv * gamma[tid + 256] + beta[tid + 256];
}

extern "C" void kernel_launch(void* const* d_in, const int* in_sizes, int n_in,
                              void* d_out, int out_size, void* d_ws, size_t ws_size,
                              hipStream_t stream) {
    const float* query = (const float*)d_in[0];
    const float* enc   = (const float*)d_in[1];
    const int*   slen  = (const int*)d_in[2];
    const float* W_h   = (const float*)d_in[3];
    const float* W_s   = (const float*)d_in[4];
    const float* v     = (const float*)d_in[5];
    const float* W_out = (const float*)d_in[6];
    const float* b_out = (const float*)d_in[7];
    const float* gamma = (const float*)d_in[8];
    const float* beta  = (const float*)d_in[9];
    float* out = (float*)d_out;

    // ---- workspace map, non-aliased (d_ws = 256 MB) ----
    char* base = (char*)d_ws;
    short* qb     = (short*)(base + 0x000000);   // 512K bf16 query
    short* wsb    = (short*)(base + 0x080000);   // 512K bf16 W_s
    short* whb    = (short*)(base + 0x100000);   // 512K bf16 W_h
    short* wob    = (short*)(base + 0x180000);   // 1M   bf16 W_out
    short* eb     = (short*)(base + 0x280000);   // 2M   bf16 enc
    float* qe     = (float*)(base + 0x480000);   // 1M   f32 Eq
    float* ke     = (float*)(base + 0x580000);   // 4M   f32 Ek
    float* scoreh = (float*)(base + 0x980000);   // 4M   f32 score quarters
    short* U      = (short*)(base + 0xD80000);   // 512K bf16 unnormalized attn
    short* ewt    = (short*)(base + 0xE00000);   // 2M   bf16 enc@Wo1 (per-b [o][s])
    float* qw     = (float*)(base + 0x1000000);  // 1M   f32 q@Wo2^T
    float* Z      = (float*)(base + 0x1100000);  // 2K   f32 row normalizers
    float* pre    = (float*)(base + 0x1101000);  // 1M   f32 pre-LN

    cvt_all<<<dim3(1152), dim3(256), 0, stream>>>(query, W_s, W_h, W_out, enc,
                                                  qb, wsb, whb, wob, eb);
    proj_mega<<<dim3(2560), dim3(64), 0, stream>>>(qb, eb, wsb, whb, wob, slen,
                                                   qe, ke, ewt, qw);
    score_v4<<<dim3(32, 16, 16), dim3(64), 0, stream>>>(qe, ke, v, slen, scoreh);
    combine_k<<<dim3(128), dim3(256), 0, stream>>>(scoreh, slen, U, Z);
    mfma_out2<<<dim3(16, 16), dim3(64), 0, stream>>>(U, ewt, qw, Z, slen, b_out, pre);
    ln_out<<<dim3(B * T), dim3(256), 0, stream>>>(pre, gamma, beta, out);
}